// Round 2
// baseline (76.170 us; speedup 1.0000x reference)
//
#include <hip/hip_runtime.h>
#include <math.h>

#define N 512
#define D 256
#define ITILE 2
#define TPB 512
#define NPAIRS 261632.0f  // 512*511

__constant__ float kRad2Deg = 57.29577951308232f; // 180/pi

// ---------------------------------------------------------------------------
// Kernel 1: per-row pose prep. labels[i] = 6d rot || 3d translation.
// ---------------------------------------------------------------------------
__global__ void prep_kernel(const float* __restrict__ labels,
                            float* __restrict__ rot,
                            float* __restrict__ tvec) {
    int i = blockIdx.x * blockDim.x + threadIdx.x;
    if (i >= N) return;
    const float* p = labels + i * 9;
    float a1x = p[0], a1y = p[1], a1z = p[2];
    float a2x = p[3], a2y = p[4], a2z = p[5];
    float n1 = sqrtf(a1x * a1x + a1y * a1y + a1z * a1z);
    float b1x = a1x / n1, b1y = a1y / n1, b1z = a1z / n1;
    float dp = b1x * a2x + b1y * a2y + b1z * a2z;
    float cx = a2x - dp * b1x, cy = a2y - dp * b1y, cz = a2z - dp * b1z;
    float n2 = sqrtf(cx * cx + cy * cy + cz * cz);
    float b2x = cx / n2, b2y = cy / n2, b2z = cz / n2;
    float b3x = b1y * b2z - b1z * b2y;
    float b3y = b1z * b2x - b1x * b2z;
    float b3z = b1x * b2y - b1y * b2x;
    float det = b1x * (b2y * b3z - b2z * b3y)
              - b1y * (b2x * b3z - b2z * b3x)
              + b1z * (b2x * b3y - b2y * b3x);
    float inv = 1.0f / cbrtf(det);
    float* r = rot + i * 9;
    r[0] = b1x * inv; r[1] = b1y * inv; r[2] = b1z * inv;
    r[3] = b2x * inv; r[4] = b2y * inv; r[5] = b2z * inv;
    r[6] = b3x * inv; r[7] = b3y * inv; r[8] = b3z * inv;
    tvec[i * 3 + 0] = p[6];
    tvec[i * 3 + 1] = p[7];
    tvec[i * 3 + 2] = p[8];
}

// ---------------------------------------------------------------------------
// Kernel 2 (A): materialize row data E/TD/SD (512x512 each, L2-resident) and
// fold Sum(L) into acc[0]. Row-max subtraction is a provable no-op (diag
// logit == 0, off-diag <= 0). Diagonal E forced to 0 == diagonal removal.
// ---------------------------------------------------------------------------
__global__ __launch_bounds__(TPB) void rowdata_kernel(
        const float* __restrict__ f,
        const float* __restrict__ rot,
        const float* __restrict__ tvec,
        float* __restrict__ E,
        float* __restrict__ TD,
        float* __restrict__ SD,
        float* __restrict__ acc) {
    __shared__ __attribute__((aligned(16))) float lds_fi[ITILE * D];
    __shared__ float red[TPB / 64];

    const int j  = threadIdx.x;
    const int i0 = blockIdx.x * ITILE;

    lds_fi[j] = f[i0 * D + j];       // TPB == ITILE*D
    __syncthreads();

    float d2[ITILE];
#pragma unroll
    for (int r = 0; r < ITILE; ++r) d2[r] = 0.0f;

    const float4* __restrict__ fj4 = (const float4*)(f + j * D);
#pragma unroll 8
    for (int kk = 0; kk < D / 4; ++kk) {
        float4 v = fj4[kk];
#pragma unroll
        for (int r = 0; r < ITILE; ++r) {
            const float4 fi = *(const float4*)&lds_fi[r * D + kk * 4];
            float dx = fi.x - v.x, dy = fi.y - v.y;
            float dz = fi.z - v.z, dw = fi.w - v.w;
            d2[r] += dx * dx + dy * dy + dz * dz + dw * dw;
        }
    }

    float rj[9];
#pragma unroll
    for (int c = 0; c < 9; ++c) rj[c] = rot[j * 9 + c];
    const float tjx = tvec[j * 3 + 0];
    const float tjy = tvec[j * 3 + 1];
    const float tjz = tvec[j * 3 + 2];

    float lsum = 0.0f;
#pragma unroll
    for (int r = 0; r < ITILE; ++r) {
        const int i = i0 + r;
        float tr = 0.0f;
#pragma unroll
        for (int c = 0; c < 9; ++c) tr += rot[i * 9 + c] * rj[c];  // uniform i
        float ct = (tr - 1.0f) * 0.5f;
        ct = fminf(1.0f, fmaxf(-1.0f, ct));
        float theta = acosf(ct) * kRad2Deg;

        float dx = tvec[i * 3 + 0] - tjx;
        float dy = tvec[i * 3 + 1] - tjy;
        float dz = tvec[i * 3 + 2] - tjz;
        float sd2 = dx * dx + dy * dy + dz * dz;
        float shift = (sd2 > 0.0f ? sqrtf(sd2) : 0.0f) * 100.0f;

        float dist = (d2[r] > 0.0f ? sqrtf(d2[r]) : 0.0f);
        float L = -dist * 0.5f;                 // TEMPERATURE = 2.0; rowmax == 0
        float Ev = (j == i) ? 0.0f : expf(L);   // diag weight 0 == diag removal
        E[i * N + j]  = Ev;
        TD[i * N + j] = theta;
        SD[i * N + j] = shift;
        lsum += L;                               // L_ii = 0 exactly: harmless
    }

    // block reduction of Sum(L) -> one atomic per block
#pragma unroll
    for (int off = 32; off > 0; off >>= 1) lsum += __shfl_down(lsum, off, 64);
    const int lane = j & 63, wid = j >> 6;
    if (lane == 0) red[wid] = lsum;
    __syncthreads();
    if (j == 0) {
        float s = 0.0f;
#pragma unroll
        for (int w = 0; w < TPB / 64; ++w) s += red[w];
        atomicAdd(acc, s);
    }
}

// ---------------------------------------------------------------------------
// Kernel 3 (B): denominators. One thread per (i,j) pair; 1024 blocks x 256
// threads -> 16 waves/CU. The k-loop reads row data at wave-uniform global
// addresses -> compiler scalarizes to s_load (separate pipe), so the inner
// loop is pure VALU against SGPR operands. Zero LDS traffic.
// ---------------------------------------------------------------------------
__global__ __launch_bounds__(256) void denom_kernel(
        const float* __restrict__ E,
        const float* __restrict__ TD,
        const float* __restrict__ SD,
        float* __restrict__ acc) {
    __shared__ float red[4];
    const int i = blockIdx.x >> 1;
    const int j = ((blockIdx.x & 1) << 8) + threadIdx.x;

    const float* __restrict__ er = E  + i * N;
    const float* __restrict__ tr = TD + i * N;
    const float* __restrict__ sr = SD + i * N;

    const float tdj = tr[j];   // coalesced per-thread load
    const float sdj = sr[j];

    float dt = 0.0f, ds = 0.0f;
#pragma unroll 4
    for (int k = 0; k < N; k += 4) {
        const float4 e4 = *(const float4*)(er + k);  // uniform -> s_load_dwordx4
        const float4 t4 = *(const float4*)(tr + k);
        const float4 s4 = *(const float4*)(sr + k);
        dt += (t4.x >= tdj) ? e4.x : 0.0f;
        dt += (t4.y >= tdj) ? e4.y : 0.0f;
        dt += (t4.z >= tdj) ? e4.z : 0.0f;
        dt += (t4.w >= tdj) ? e4.w : 0.0f;
        ds += (s4.x >= sdj) ? e4.x : 0.0f;
        ds += (s4.y >= sdj) ? e4.y : 0.0f;
        ds += (s4.z >= sdj) ? e4.z : 0.0f;
        ds += (s4.w >= sdj) ? e4.w : 0.0f;
    }

    // j == i is not a valid pair (threshold row removed by jidx); contributes 0.
    float v = (j == i) ? 0.0f : -0.5f * (logf(dt) + logf(ds));

#pragma unroll
    for (int off = 32; off > 0; off >>= 1) v += __shfl_down(v, off, 64);
    const int lane = threadIdx.x & 63, wid = threadIdx.x >> 6;
    if (lane == 0) red[wid] = v;
    __syncthreads();
    if (threadIdx.x == 0) {
        float s = red[0] + red[1] + red[2] + red[3];
        atomicAdd(acc, s);
    }
}

// ---------------------------------------------------------------------------
// Kernel 4: finalize scalar.
// ---------------------------------------------------------------------------
__global__ void finalize_kernel(const float* __restrict__ acc,
                                float* __restrict__ out) {
    out[0] = -acc[0] / NPAIRS;
}

extern "C" void kernel_launch(void* const* d_in, const int* in_sizes, int n_in,
                              void* d_out, int out_size, void* d_ws, size_t ws_size,
                              hipStream_t stream) {
    const float* f      = (const float*)d_in[0];  // (512, 256) fp32
    const float* labels = (const float*)d_in[1];  // (512, 9)   fp32
    float* out = (float*)d_out;                   // scalar fp32
    float* ws  = (float*)d_ws;

    float* rot  = ws;                      // 512*9
    float* tvec = rot + N * 9;             // 512*3
    float* acc  = tvec + N * 3;            // 1 (+3 pad)
    float* E    = acc + 4;                 // 512*512
    float* TD   = E + N * N;               // 512*512
    float* SD   = TD + N * N;              // 512*512

    hipMemsetAsync(acc, 0, sizeof(float), stream);
    prep_kernel<<<(N + 255) / 256, 256, 0, stream>>>(labels, rot, tvec);
    rowdata_kernel<<<N / ITILE, TPB, 0, stream>>>(f, rot, tvec, E, TD, SD, acc);
    denom_kernel<<<N * 2, 256, 0, stream>>>(E, TD, SD, acc);
    finalize_kernel<<<1, 1, 0, stream>>>(acc, out);
}

// Round 3
// 71.518 us; speedup vs baseline: 1.0650x; 1.0650x over previous
//
#include <hip/hip_runtime.h>
#include <math.h>

#define N 512
#define D 256
#define ITILE 2
#define TPB 512
#define NPAIRS 261632.0f  // 512*511

__constant__ float kRad2Deg = 57.29577951308232f; // 180/pi

// ---------------------------------------------------------------------------
// Kernel 1: per-row pose prep. labels[i] = 6d rot || 3d translation.
// ---------------------------------------------------------------------------
__global__ void prep_kernel(const float* __restrict__ labels,
                            float* __restrict__ rot,
                            float* __restrict__ tvec) {
    int i = blockIdx.x * blockDim.x + threadIdx.x;
    if (i >= N) return;
    const float* p = labels + i * 9;
    float a1x = p[0], a1y = p[1], a1z = p[2];
    float a2x = p[3], a2y = p[4], a2z = p[5];
    float n1 = sqrtf(a1x * a1x + a1y * a1y + a1z * a1z);
    float b1x = a1x / n1, b1y = a1y / n1, b1z = a1z / n1;
    float dp = b1x * a2x + b1y * a2y + b1z * a2z;
    float cx = a2x - dp * b1x, cy = a2y - dp * b1y, cz = a2z - dp * b1z;
    float n2 = sqrtf(cx * cx + cy * cy + cz * cz);
    float b2x = cx / n2, b2y = cy / n2, b2z = cz / n2;
    float b3x = b1y * b2z - b1z * b2y;
    float b3y = b1z * b2x - b1x * b2z;
    float b3z = b1x * b2y - b1y * b2x;
    float det = b1x * (b2y * b3z - b2z * b3y)
              - b1y * (b2x * b3z - b2z * b3x)
              + b1z * (b2x * b3y - b2y * b3x);
    float inv = 1.0f / cbrtf(det);
    float* r = rot + i * 9;
    r[0] = b1x * inv; r[1] = b1y * inv; r[2] = b1z * inv;
    r[3] = b2x * inv; r[4] = b2y * inv; r[5] = b2z * inv;
    r[6] = b3x * inv; r[7] = b3y * inv; r[8] = b3z * inv;
    tvec[i * 3 + 0] = p[6];
    tvec[i * 3 + 1] = p[7];
    tvec[i * 3 + 2] = p[8];
}

// ---------------------------------------------------------------------------
// Kernel 2 (A): materialize row data E/TD/SD (512x512 each, L2-resident) and
// fold Sum(L) into acc[0]. Row-max subtraction is a provable no-op (diag
// logit == 0, off-diag <= 0). Diagonal E forced to 0 == diagonal removal.
// Distance loop is FULLY unrolled so the compiler software-pipelines the
// 64 float4 global loads (round-2's unroll-8 was latency-exposed).
// ---------------------------------------------------------------------------
__global__ __launch_bounds__(TPB) void rowdata_kernel(
        const float* __restrict__ f,
        const float* __restrict__ rot,
        const float* __restrict__ tvec,
        float* __restrict__ E,
        float* __restrict__ TD,
        float* __restrict__ SD,
        float* __restrict__ acc) {
    __shared__ __attribute__((aligned(16))) float lds_fi[ITILE * D];
    __shared__ float red[TPB / 64];

    const int j  = threadIdx.x;
    const int i0 = blockIdx.x * ITILE;

    lds_fi[j] = f[i0 * D + j];       // TPB == ITILE*D
    __syncthreads();

    float d2[ITILE];
#pragma unroll
    for (int r = 0; r < ITILE; ++r) d2[r] = 0.0f;

    const float4* __restrict__ fj4 = (const float4*)(f + j * D);
#pragma unroll
    for (int kk = 0; kk < D / 4; ++kk) {
        float4 v = fj4[kk];
#pragma unroll
        for (int r = 0; r < ITILE; ++r) {
            const float4 fi = *(const float4*)&lds_fi[r * D + kk * 4];
            float dx = fi.x - v.x, dy = fi.y - v.y;
            float dz = fi.z - v.z, dw = fi.w - v.w;
            d2[r] += dx * dx + dy * dy + dz * dz + dw * dw;
        }
    }

    float rj[9];
#pragma unroll
    for (int c = 0; c < 9; ++c) rj[c] = rot[j * 9 + c];
    const float tjx = tvec[j * 3 + 0];
    const float tjy = tvec[j * 3 + 1];
    const float tjz = tvec[j * 3 + 2];

    float lsum = 0.0f;
#pragma unroll
    for (int r = 0; r < ITILE; ++r) {
        const int i = i0 + r;
        float tr = 0.0f;
#pragma unroll
        for (int c = 0; c < 9; ++c) tr += rot[i * 9 + c] * rj[c];  // uniform i
        float ct = (tr - 1.0f) * 0.5f;
        ct = fminf(1.0f, fmaxf(-1.0f, ct));
        float theta = acosf(ct) * kRad2Deg;

        float dx = tvec[i * 3 + 0] - tjx;
        float dy = tvec[i * 3 + 1] - tjy;
        float dz = tvec[i * 3 + 2] - tjz;
        float sd2 = dx * dx + dy * dy + dz * dz;
        float shift = (sd2 > 0.0f ? sqrtf(sd2) : 0.0f) * 100.0f;

        float dist = (d2[r] > 0.0f ? sqrtf(d2[r]) : 0.0f);
        float L = -dist * 0.5f;                 // TEMPERATURE = 2.0; rowmax == 0
        float Ev = (j == i) ? 0.0f : expf(L);   // diag weight 0 == diag removal
        E[i * N + j]  = Ev;
        TD[i * N + j] = theta;
        SD[i * N + j] = shift;
        lsum += L;                               // L_ii = 0 exactly: harmless
    }

#pragma unroll
    for (int off = 32; off > 0; off >>= 1) lsum += __shfl_down(lsum, off, 64);
    const int lane = j & 63, wid = j >> 6;
    if (lane == 0) red[wid] = lsum;
    __syncthreads();
    if (j == 0) {
        float s = 0.0f;
#pragma unroll
        for (int w = 0; w < TPB / 64; ++w) s += red[w];
        atomicAdd(acc, s);
    }
}

// ---------------------------------------------------------------------------
// Kernel 3 (B): denominators, register-broadcast design.
// Block = one row i, 256 threads; thread handles j = tid and j+256 (JTILE=2).
// Each wave loads the row's E/TD/SD (512 floats each) into 24 VGPRs
// (lane l, reg r holds element r*64+l), then the 512-iteration k-loop is
// PURE REGISTER work: v_readlane broadcasts + v_cmp/v_cndmask/v_add.
// Zero memory operations inside the hot loop.
// ---------------------------------------------------------------------------
__global__ __launch_bounds__(256) void denom_kernel(
        const float* __restrict__ E,
        const float* __restrict__ TD,
        const float* __restrict__ SD,
        float* __restrict__ acc) {
    __shared__ float red[4];
    const int i    = blockIdx.x;
    const int j0   = threadIdx.x;
    const int j1   = threadIdx.x + 256;
    const int lane = threadIdx.x & 63;

    const float* __restrict__ er = E  + i * N;
    const float* __restrict__ tr = TD + i * N;
    const float* __restrict__ sr = SD + i * N;

    // wave-resident row data: 24 VGPRs
    float vE[8], vT[8], vS[8];
#pragma unroll
    for (int r = 0; r < 8; ++r) {
        vE[r] = er[r * 64 + lane];
        vT[r] = tr[r * 64 + lane];
        vS[r] = sr[r * 64 + lane];
    }

    const float td0 = tr[j0], sd0 = sr[j0];
    const float td1 = tr[j1], sd1 = sr[j1];

    float dt0 = 0.0f, ds0 = 0.0f, dt1 = 0.0f, ds1 = 0.0f;
#pragma unroll
    for (int r = 0; r < 8; ++r) {
#pragma unroll 4
        for (int l = 0; l < 64; ++l) {
            const float e = __int_as_float(
                __builtin_amdgcn_readlane(__float_as_int(vE[r]), l));
            const float t = __int_as_float(
                __builtin_amdgcn_readlane(__float_as_int(vT[r]), l));
            const float s = __int_as_float(
                __builtin_amdgcn_readlane(__float_as_int(vS[r]), l));
            dt0 += (t >= td0) ? e : 0.0f;
            ds0 += (s >= sd0) ? e : 0.0f;
            dt1 += (t >= td1) ? e : 0.0f;
            ds1 += (s >= sd1) ? e : 0.0f;
        }
    }

    // j == i is not a valid pair (threshold row removed by jidx); contributes 0.
    float v = 0.0f;
    if (j0 != i) v += -0.5f * (logf(dt0) + logf(ds0));
    if (j1 != i) v += -0.5f * (logf(dt1) + logf(ds1));

#pragma unroll
    for (int off = 32; off > 0; off >>= 1) v += __shfl_down(v, off, 64);
    const int wid = threadIdx.x >> 6;
    if (lane == 0) red[wid] = v;
    __syncthreads();
    if (threadIdx.x == 0) {
        float s = red[0] + red[1] + red[2] + red[3];
        atomicAdd(acc, s);
    }
}

// ---------------------------------------------------------------------------
// Kernel 4: finalize scalar.
// ---------------------------------------------------------------------------
__global__ void finalize_kernel(const float* __restrict__ acc,
                                float* __restrict__ out) {
    out[0] = -acc[0] / NPAIRS;
}

extern "C" void kernel_launch(void* const* d_in, const int* in_sizes, int n_in,
                              void* d_out, int out_size, void* d_ws, size_t ws_size,
                              hipStream_t stream) {
    const float* f      = (const float*)d_in[0];  // (512, 256) fp32
    const float* labels = (const float*)d_in[1];  // (512, 9)   fp32
    float* out = (float*)d_out;                   // scalar fp32
    float* ws  = (float*)d_ws;

    float* rot  = ws;                      // 512*9
    float* tvec = rot + N * 9;             // 512*3
    float* acc  = tvec + N * 3;            // 1 (+3 pad)
    float* E    = acc + 4;                 // 512*512
    float* TD   = E + N * N;               // 512*512
    float* SD   = TD + N * N;              // 512*512

    hipMemsetAsync(acc, 0, sizeof(float), stream);
    prep_kernel<<<(N + 255) / 256, 256, 0, stream>>>(labels, rot, tvec);
    rowdata_kernel<<<N / ITILE, TPB, 0, stream>>>(f, rot, tvec, E, TD, SD, acc);
    denom_kernel<<<N, 256, 0, stream>>>(E, TD, SD, acc);
    finalize_kernel<<<1, 1, 0, stream>>>(acc, out);
}

// Round 4
// 57.269 us; speedup vs baseline: 1.3300x; 1.2488x over previous
//
#include <hip/hip_runtime.h>
#include <math.h>

#define N 512
#define D 256
#define ITILE 2
#define TPB 512
#define NPAIRS 261632.0f  // 512*511

__constant__ float kRad2Deg = 57.29577951308232f; // 180/pi

// ---------------------------------------------------------------------------
// Kernel 1: per-row pose prep. labels[i] = 6d rot || 3d translation.
// Thread 0 also zeroes the accumulator (replaces the hipMemsetAsync launch).
// ---------------------------------------------------------------------------
__global__ void prep_kernel(const float* __restrict__ labels,
                            float* __restrict__ rot,
                            float* __restrict__ tvec,
                            float* __restrict__ acc) {
    int i = blockIdx.x * blockDim.x + threadIdx.x;
    if (i == 0) acc[0] = 0.0f;          // stream-ordered before rowdata's atomics
    if (i >= N) return;
    const float* p = labels + i * 9;
    float a1x = p[0], a1y = p[1], a1z = p[2];
    float a2x = p[3], a2y = p[4], a2z = p[5];
    float n1 = sqrtf(a1x * a1x + a1y * a1y + a1z * a1z);
    float b1x = a1x / n1, b1y = a1y / n1, b1z = a1z / n1;
    float dp = b1x * a2x + b1y * a2y + b1z * a2z;
    float cx = a2x - dp * b1x, cy = a2y - dp * b1y, cz = a2z - dp * b1z;
    float n2 = sqrtf(cx * cx + cy * cy + cz * cz);
    float b2x = cx / n2, b2y = cy / n2, b2z = cz / n2;
    float b3x = b1y * b2z - b1z * b2y;
    float b3y = b1z * b2x - b1x * b2z;
    float b3z = b1x * b2y - b1y * b2x;
    float det = b1x * (b2y * b3z - b2z * b3y)
              - b1y * (b2x * b3z - b2z * b3x)
              + b1z * (b2x * b3y - b2y * b3x);
    float inv = 1.0f / cbrtf(det);
    float* r = rot + i * 9;
    r[0] = b1x * inv; r[1] = b1y * inv; r[2] = b1z * inv;
    r[3] = b2x * inv; r[4] = b2y * inv; r[5] = b2z * inv;
    r[6] = b3x * inv; r[7] = b3y * inv; r[8] = b3z * inv;
    tvec[i * 3 + 0] = p[6];
    tvec[i * 3 + 1] = p[7];
    tvec[i * 3 + 2] = p[8];
}

// ---------------------------------------------------------------------------
// Kernel 2: materialize row data E/TD/SD (512x512 each, L2-resident) and
// fold Sum(L) into acc[0]. Row-max subtraction is a provable no-op (diag
// logit == 0, off-diag <= 0). Diagonal E forced to 0 == diagonal removal.
// ---------------------------------------------------------------------------
__global__ __launch_bounds__(TPB) void rowdata_kernel(
        const float* __restrict__ f,
        const float* __restrict__ rot,
        const float* __restrict__ tvec,
        float* __restrict__ E,
        float* __restrict__ TD,
        float* __restrict__ SD,
        float* __restrict__ acc) {
    __shared__ __attribute__((aligned(16))) float lds_fi[ITILE * D];
    __shared__ float red[TPB / 64];

    const int j  = threadIdx.x;
    const int i0 = blockIdx.x * ITILE;

    lds_fi[j] = f[i0 * D + j];       // TPB == ITILE*D
    __syncthreads();

    float d2[ITILE];
#pragma unroll
    for (int r = 0; r < ITILE; ++r) d2[r] = 0.0f;

    const float4* __restrict__ fj4 = (const float4*)(f + j * D);
#pragma unroll
    for (int kk = 0; kk < D / 4; ++kk) {
        float4 v = fj4[kk];
#pragma unroll
        for (int r = 0; r < ITILE; ++r) {
            const float4 fi = *(const float4*)&lds_fi[r * D + kk * 4];
            float dx = fi.x - v.x, dy = fi.y - v.y;
            float dz = fi.z - v.z, dw = fi.w - v.w;
            d2[r] += dx * dx + dy * dy + dz * dz + dw * dw;
        }
    }

    float rj[9];
#pragma unroll
    for (int c = 0; c < 9; ++c) rj[c] = rot[j * 9 + c];
    const float tjx = tvec[j * 3 + 0];
    const float tjy = tvec[j * 3 + 1];
    const float tjz = tvec[j * 3 + 2];

    float lsum = 0.0f;
#pragma unroll
    for (int r = 0; r < ITILE; ++r) {
        const int i = i0 + r;
        float tr = 0.0f;
#pragma unroll
        for (int c = 0; c < 9; ++c) tr += rot[i * 9 + c] * rj[c];  // uniform i
        float ct = (tr - 1.0f) * 0.5f;
        ct = fminf(1.0f, fmaxf(-1.0f, ct));
        float theta = acosf(ct) * kRad2Deg;

        float dx = tvec[i * 3 + 0] - tjx;
        float dy = tvec[i * 3 + 1] - tjy;
        float dz = tvec[i * 3 + 2] - tjz;
        float sd2 = dx * dx + dy * dy + dz * dz;
        float shift = (sd2 > 0.0f ? sqrtf(sd2) : 0.0f) * 100.0f;

        float dist = (d2[r] > 0.0f ? sqrtf(d2[r]) : 0.0f);
        float L = -dist * 0.5f;                 // TEMPERATURE = 2.0; rowmax == 0
        float Ev = (j == i) ? 0.0f : expf(L);   // diag weight 0 == diag removal
        E[i * N + j]  = Ev;
        TD[i * N + j] = theta;
        SD[i * N + j] = shift;
        lsum += L;                               // L_ii = 0 exactly: harmless
    }

#pragma unroll
    for (int off = 32; off > 0; off >>= 1) lsum += __shfl_down(lsum, off, 64);
    const int lane = j & 63, wid = j >> 6;
    if (lane == 0) red[wid] = lsum;
    __syncthreads();
    if (j == 0) {
        float s = 0.0f;
#pragma unroll
        for (int w = 0; w < TPB / 64; ++w) s += red[w];
        atomicAdd(acc, s);
    }
}

// ---------------------------------------------------------------------------
// Kernel 3: sort-based denominators. Block = one row i, 256 threads.
// denom_t[i][j] = sum_k E[k]*[TD[k] >= TD[j]]  ==  suffix-sum of E in
// TD-sorted order, evaluated at j's tie-run start (lb). Sum of log-denoms
// over ALL positions needs no indices; the diagonal's (excluded-j) term is
// computed directly and subtracted. Both criteria (TD, SD) are sorted in
// the same bitonic phase loop to share barriers. TD,SD >= 0 so float-bit
// order == value order (uint keys).
// ---------------------------------------------------------------------------
__global__ __launch_bounds__(256) void sortdenom_kernel(
        const float* __restrict__ E,
        const float* __restrict__ TD,
        const float* __restrict__ SD,
        float* __restrict__ acc) {
    __shared__ unsigned kT[512], kS[512];
    __shared__ float pT[512], pS[512];      // payload E (sorted with key)
    __shared__ float sT[512], sS[512];      // suffix sums
    __shared__ int   lT[512], lS[512];      // tie-run-start (lb) max-scan
    __shared__ float redA[4], redB[4];
    __shared__ float diag_part_sh;

    const int t = threadIdx.x;
    const int i = blockIdx.x;
    const float* __restrict__ er = E  + i * N;
    const float* __restrict__ tr = TD + i * N;
    const float* __restrict__ sr = SD + i * N;

    const float e0 = er[t], e1 = er[t + 256];
    const float t0 = tr[t], t1 = tr[t + 256];
    const float s0 = sr[t], s1 = sr[t + 256];
    const float dT = tr[i], dS = sr[i];     // diagonal thresholds

    // ---- direct diag denominators (the excluded j==i terms) ----
    float dtd = ((t0 >= dT) ? e0 : 0.0f) + ((t1 >= dT) ? e1 : 0.0f);
    float dsd = ((s0 >= dS) ? e0 : 0.0f) + ((s1 >= dS) ? e1 : 0.0f);
#pragma unroll
    for (int off = 32; off > 0; off >>= 1) {
        dtd += __shfl_down(dtd, off, 64);
        dsd += __shfl_down(dsd, off, 64);
    }
    const int lane = t & 63, wid = t >> 6;
    if (lane == 0) { redA[wid] = dtd; redB[wid] = dsd; }

    // ---- stage sort arrays ----
    kT[t] = __float_as_uint(t0); kT[t + 256] = __float_as_uint(t1);
    kS[t] = __float_as_uint(s0); kS[t + 256] = __float_as_uint(s1);
    pT[t] = e0; pT[t + 256] = e1;
    pS[t] = e0; pS[t + 256] = e1;
    __syncthreads();

    if (t == 0) {
        float a = redA[0] + redA[1] + redA[2] + redA[3];
        float b = redB[0] + redB[1] + redB[2] + redB[3];
        diag_part_sh = 0.5f * (logf(a) + logf(b));
    }

    // ---- bitonic sort (ascending), both criteria under shared barriers ----
    for (unsigned k = 2; k <= 512; k <<= 1) {
        for (unsigned jj = k >> 1; jj >= 1; jj >>= 1) {
            __syncthreads();
            const unsigned a = ((t & ~(jj - 1)) << 1) | (t & (jj - 1));
            const unsigned b = a | jj;
            const bool up = ((a & k) == 0);
            {
                unsigned ka = kT[a], kb = kT[b];
                bool sw = up ? (ka > kb) : (ka < kb);
                if (sw) {
                    kT[a] = kb; kT[b] = ka;
                    float tp = pT[a]; pT[a] = pT[b]; pT[b] = tp;
                }
            }
            {
                unsigned ka = kS[a], kb = kS[b];
                bool sw = up ? (ka > kb) : (ka < kb);
                if (sw) {
                    kS[a] = kb; kS[b] = ka;
                    float tp = pS[a]; pS[a] = pS[b]; pS[b] = tp;
                }
            }
        }
    }
    __syncthreads();

    // ---- init suffix-sum and lb arrays ----
    sT[t] = pT[t]; sT[t + 256] = pT[t + 256];
    sS[t] = pS[t]; sS[t + 256] = pS[t + 256];
    lT[t]       = (t == 0 || kT[t - 1]   != kT[t])       ? t         : 0;
    lT[t + 256] = (kT[t + 255] != kT[t + 256])           ? (t + 256) : 0;
    lS[t]       = (t == 0 || kS[t - 1]   != kS[t])       ? t         : 0;
    lS[t + 256] = (kS[t + 255] != kS[t + 256])           ? (t + 256) : 0;
    __syncthreads();

    // ---- Hillis-Steele: inclusive suffix-sum (float) + inclusive max-scan
    //      (lb), both criteria, shared barriers. 9 steps. ----
    for (int st = 1; st < 512; st <<= 1) {
        float a0 = (t + st < 512) ? sT[t + st] : 0.0f;
        float a1 = (t + 256 + st < 512) ? sT[t + 256 + st] : 0.0f;
        float b0 = (t + st < 512) ? sS[t + st] : 0.0f;
        float b1 = (t + 256 + st < 512) ? sS[t + 256 + st] : 0.0f;
        int   m0 = (t >= st) ? lT[t - st] : 0;
        int   m1 = lT[t + 256 - st];        // t+256 >= st always (st <= 256)
        int   n0 = (t >= st) ? lS[t - st] : 0;
        int   n1 = lS[t + 256 - st];
        __syncthreads();
        sT[t] += a0; sT[t + 256] += a1;
        sS[t] += b0; sS[t + 256] += b1;
        lT[t] = max(lT[t], m0); lT[t + 256] = max(lT[t + 256], m1);
        lS[t] = max(lS[t], n0); lS[t + 256] = max(lS[t + 256], n1);
        __syncthreads();
    }

    // ---- per-position log terms, block reduce, one atomic ----
    float term = logf(sT[lT[t]]) + logf(sT[lT[t + 256]])
               + logf(sS[lS[t]]) + logf(sS[lS[t + 256]]);
#pragma unroll
    for (int off = 32; off > 0; off >>= 1) term += __shfl_down(term, off, 64);
    __syncthreads();                        // redA reuse hazard
    if (lane == 0) redA[wid] = term;
    __syncthreads();
    if (t == 0) {
        float tt = redA[0] + redA[1] + redA[2] + redA[3];
        // contribution: -0.5 * (sum over j!=i of (log dt + log ds))
        atomicAdd(acc, -0.5f * tt + diag_part_sh);
    }
}

// ---------------------------------------------------------------------------
// Kernel 4: finalize scalar.
// ---------------------------------------------------------------------------
__global__ void finalize_kernel(const float* __restrict__ acc,
                                float* __restrict__ out) {
    out[0] = -acc[0] / NPAIRS;
}

extern "C" void kernel_launch(void* const* d_in, const int* in_sizes, int n_in,
                              void* d_out, int out_size, void* d_ws, size_t ws_size,
                              hipStream_t stream) {
    const float* f      = (const float*)d_in[0];  // (512, 256) fp32
    const float* labels = (const float*)d_in[1];  // (512, 9)   fp32
    float* out = (float*)d_out;                   // scalar fp32
    float* ws  = (float*)d_ws;

    float* rot  = ws;                      // 512*9
    float* tvec = rot + N * 9;             // 512*3
    float* acc  = tvec + N * 3;            // 1 (+3 pad)
    float* E    = acc + 4;                 // 512*512
    float* TD   = E + N * N;               // 512*512
    float* SD   = TD + N * N;              // 512*512

    prep_kernel<<<2, 256, 0, stream>>>(labels, rot, tvec, acc);
    rowdata_kernel<<<N / ITILE, TPB, 0, stream>>>(f, rot, tvec, E, TD, SD, acc);
    sortdenom_kernel<<<N, 256, 0, stream>>>(E, TD, SD, acc);
    finalize_kernel<<<1, 1, 0, stream>>>(acc, out);
}